// Round 1
// baseline (263.141 us; speedup 1.0000x reference)
//
#include <hip/hip_runtime.h>
#include <hip/hip_bf16.h>

#define NN    1024
#define DD    128
#define TS    64         // tile edge
#define PITCH 136        // bf16 elems per LDS row: 128 + 8 pad (keeps rows 16B-aligned)
#define NSMALL 16
#define GRID_MAIN 4096   // 16 batches * 16x16 tiles
#define GRID_ALL  4112

typedef __bf16 bf16_t;
typedef bf16_t bf16x8 __attribute__((ext_vector_type(8)));
typedef float  f32x4  __attribute__((ext_vector_type(4)));

// ws layout (floats):
// [0] coord_sum  [1] reg_sum  [2] count_loss_sum  [3] bce_sum
// [4+b] pos_sum  [20+b] pos_cnt  [36+b] neg_sum  [52+b] neg_cnt  -> 68 floats

__device__ __forceinline__ void loss_elem(float l, float a, float s, int grow, int gcol,
    float& bsum, float& poss, float& posc, float& negs, float& negc) {
  bsum += fmaxf(l, 0.f) - l * a + __logf(1.f + __expf(-fabsf(l)));
  if (a > 0.5f) {
    poss += s; posc += 1.f;
  } else if (grow != gcol) {
    negc += 1.f;
    if (s < 1.f) {                    // essentially never for random 128-d features
      float d = sqrtf(fmaxf(s, 1e-12f));
      float h = 1.f - d;
      negs += h * h;
    }
  }
}

__global__ __launch_bounds__(256, 4) void fused_all(
    const float* __restrict__ logits, const float* __restrict__ adj,
    const float* __restrict__ feat,
    const float* __restrict__ pcoord, const float* __restrict__ pts,
    const float* __restrict__ masks,  const float* __restrict__ pcount,
    float* __restrict__ ws) {
  __shared__ __align__(16) bf16_t lsA[TS * PITCH];
  __shared__ __align__(16) bf16_t lsB[TS * PITCH];
  __shared__ float nrmA[TS], nrmB[TS];
  __shared__ float red[4][6];

  const int bx = blockIdx.x;
  const int t  = threadIdx.x;

  // ---------------- small-loss path: blocks 0..15 (one per batch) ----------------
  if (bx < NSMALL) {
    float coord = 0.f, cnt = 0.f;
    const int gt = bx * 256 + t;
    const float4* a4 = (const float4*)pcoord;
    const float4* b4 = (const float4*)pts;
    for (int i = gt; i < 8192; i += 4096) {
      float4 a = a4[i], c = b4[i];
      float dx = a.x-c.x, dy = a.y-c.y, dz = a.z-c.z, dw = a.w-c.w;
      coord += dx*dx + dy*dy + dz*dz + dw*dw;
    }
    const float* m = masks + bx * NN;
    for (int i = t; i < NN; i += 256) cnt += m[i];
    #pragma unroll
    for (int o = 32; o; o >>= 1) {
      coord += __shfl_xor(coord, o);
      cnt   += __shfl_xor(cnt, o);
    }
    const int lane = t & 63, w = t >> 6;
    if (lane == 0) { red[w][0] = coord; red[w][1] = cnt; }
    __syncthreads();
    if (t == 0) {
      float c = 0.f, n = 0.f;
      for (int i = 0; i < 4; ++i) { c += red[i][0]; n += red[i][1]; }
      atomicAdd(&ws[0], c);
      float d = fabsf(pcount[bx] - n);
      float term = (d < 1.f) ? 0.5f * d * d : d - 0.5f;
      atomicAdd(&ws[2], term);
    }
    return;
  }

  // ---------------- main path: 64x64 Gram+BCE tiles ----------------
  const int bm  = bx - NSMALL;
  const int b   = bm >> 8;            // 256 tiles per batch
  const int tid = bm & 255;
  const int ti  = (tid >> 4) << 6;    // tile row base
  const int tj  = (tid & 15) << 6;    // tile col base
  const bool diag = ((tid >> 4) == (tid & 15));   // 16/batch: A bands partition rows

  const int lane = t & 63, wave = t >> 6;         // 4 waves
  const int lrow = lane & 15, quad = lane >> 4;
  const float* fb = feat + (size_t)b * NN * DD;

  // ---- stage A rows [ti,ti+64) and B rows [tj,tj+64) as bf16 into LDS ----
  float regsum = 0.f;
  #pragma unroll
  for (int it = 0; it < 8; ++it) {
    int cid  = it * 256 + t;          // 0..2047 chunks of 8 floats
    int tile = cid >> 10;
    int sub  = cid & 1023;
    int row  = sub >> 4;              // 0..63
    int c8   = sub & 15;
    const float* src = fb + (size_t)((tile ? tj : ti) + row) * DD + c8 * 8;
    float4 u = *(const float4*)src;
    float4 v = *(const float4*)(src + 4);
    if (diag && tile == 0)
      regsum += u.x*u.x + u.y*u.y + u.z*u.z + u.w*u.w
              + v.x*v.x + v.y*v.y + v.z*v.z + v.w*v.w;
    bf16x8 pk;
    pk[0]=(bf16_t)u.x; pk[1]=(bf16_t)u.y; pk[2]=(bf16_t)u.z; pk[3]=(bf16_t)u.w;
    pk[4]=(bf16_t)v.x; pk[5]=(bf16_t)v.y; pk[6]=(bf16_t)v.z; pk[7]=(bf16_t)v.w;
    *(bf16x8*)((tile ? lsB : lsA) + row * PITCH + c8 * 8) = pk;
  }
  __syncthreads();

  // ---- issue the big-stream loads NOW, in MFMA fragment layout.
  // 32 dwords/thread stay in flight across norms + MFMA; the pre-barrier
  // vmcnt(0) drain then costs little. Per quad: 16 lanes x 4B = 64B contiguous.
  const size_t tb = (size_t)b * NN * NN
                  + (size_t)(ti + wave * 16 + quad * 4) * NN + (tj + lrow);
  const float* lp = logits + tb;
  const float* ap = adj + tb;
  float Lv[4][4], Av[4][4];
  #pragma unroll
  for (int r = 0; r < 4; ++r) {
    const float* lr = lp + (size_t)r * NN;
    const float* ar = ap + (size_t)r * NN;
    #pragma unroll
    for (int fc = 0; fc < 4; ++fc) {
      Lv[fc][r] = lr[fc * 16];
      Av[fc][r] = ar[fc * 16];
    }
  }

  // ---- row norms from bf16 data (consistent with MFMA dot). 2 threads/row. ----
  {
    int row = t >> 1, half = t & 1;   // 128 rows (A then B)
    const bf16_t* src = (row < TS ? lsA + row * PITCH : lsB + (row - TS) * PITCH)
                        + half * 64;
    float s = 0.f;
    #pragma unroll
    for (int c = 0; c < 8; ++c) {
      bf16x8 ch = *(const bf16x8*)(src + c * 8);
      #pragma unroll
      for (int i = 0; i < 8; ++i) { float v = (float)ch[i]; s += v * v; }
    }
    s += __shfl_xor(s, 1);
    if (half == 0) { if (row < TS) nrmA[row] = s; else nrmB[row - TS] = s; }
  }

  // ---- MFMA Gram: wave w computes rows [w*16, w*16+16) x all 64 cols ----
  f32x4 acc[4];
  #pragma unroll
  for (int fc = 0; fc < 4; ++fc) acc[fc] = (f32x4){0.f, 0.f, 0.f, 0.f};
  #pragma unroll
  for (int k0 = 0; k0 < DD; k0 += 32) {
    const int kc = k0 + quad * 8;
    bf16x8 aF = *(const bf16x8*)&lsA[(wave * 16 + lrow) * PITCH + kc];
    #pragma unroll
    for (int fc = 0; fc < 4; ++fc) {
      bf16x8 bF = *(const bf16x8*)&lsB[(fc * 16 + lrow) * PITCH + kc];
      acc[fc] = __builtin_amdgcn_mfma_f32_16x16x32_bf16(aF, bF, acc[fc], 0, 0, 0);
    }
  }
  __syncthreads();   // nrm writes visible (also drains Lv/Av, long overlapped)

  // ---- consume in fragment layout: sq in registers, no sq LDS buffer ----
  float nA[4], nB[4];
  #pragma unroll
  for (int r = 0; r < 4; ++r) nA[r] = nrmA[wave * 16 + quad * 4 + r];
  #pragma unroll
  for (int fc = 0; fc < 4; ++fc) nB[fc] = nrmB[fc * 16 + lrow];

  float bsum = 0.f, poss = 0.f, posc = 0.f, negs = 0.f, negc = 0.f;
  const int grow0 = ti + wave * 16 + quad * 4;
  const int gcol0 = tj + lrow;
  #pragma unroll
  for (int fc = 0; fc < 4; ++fc) {
    #pragma unroll
    for (int r = 0; r < 4; ++r) {
      float s = fmaxf(nA[r] + nB[fc] - 2.f * acc[fc][r], 0.f);
      loss_elem(Lv[fc][r], Av[fc][r], s, grow0 + r, gcol0 + fc * 16,
                bsum, poss, posc, negs, negc);
    }
  }

  // ---- block reduction (6 values) + per-batch atomics ----
  #pragma unroll
  for (int o = 32; o; o >>= 1) {
    bsum   += __shfl_xor(bsum, o);
    poss   += __shfl_xor(poss, o);
    posc   += __shfl_xor(posc, o);
    negs   += __shfl_xor(negs, o);
    negc   += __shfl_xor(negc, o);
    regsum += __shfl_xor(regsum, o);
  }
  if (lane == 0) {
    red[wave][0] = bsum; red[wave][1] = poss; red[wave][2] = posc;
    red[wave][3] = negs; red[wave][4] = negc; red[wave][5] = regsum;
  }
  __syncthreads();
  if (t == 0) {
    float s0=0.f,s1=0.f,s2=0.f,s3=0.f,s4=0.f,s5=0.f;
    for (int w = 0; w < 4; ++w) {
      s0 += red[w][0]; s1 += red[w][1]; s2 += red[w][2];
      s3 += red[w][3]; s4 += red[w][4]; s5 += red[w][5];
    }
    atomicAdd(&ws[3], s0);
    atomicAdd(&ws[4 + b], s1);
    atomicAdd(&ws[20 + b], s2);
    atomicAdd(&ws[36 + b], s3);
    atomicAdd(&ws[52 + b], s4);
    if (diag) atomicAdd(&ws[1], s5);
  }
}

__global__ void finalize(const float* __restrict__ ws, float* __restrict__ out) {
  if (threadIdx.x != 0 || blockIdx.x != 0) return;
  float coord = ws[0] / 32768.f;
  float reg   = ws[1] / 2097152.f;
  float cntl  = ws[2] / 16.f;
  float edge  = ws[3] / 16777216.f;
  float contra = 0.f;
  for (int b = 0; b < 16; ++b) {
    float p = ws[4 + b]  / fmaxf(ws[20 + b], 1.f);
    float n = ws[36 + b] / fmaxf(ws[52 + b], 1.f);
    contra += p + n;
  }
  contra *= (1.f / 16.f);
  float total = coord + 2.f * edge + 0.1f * cntl + 0.001f * reg + 0.1f * contra;
  out[0] = total; out[1] = coord; out[2] = edge;
  out[3] = cntl;  out[4] = reg;   out[5] = contra;
}

extern "C" void kernel_launch(void* const* d_in, const int* in_sizes, int n_in,
                              void* d_out, int out_size, void* d_ws, size_t ws_size,
                              hipStream_t stream) {
  (void)in_sizes; (void)n_in; (void)out_size; (void)ws_size;
  const float* pcoord = (const float*)d_in[0];
  const float* pts    = (const float*)d_in[1];
  const float* logits = (const float*)d_in[2];
  const float* adj    = (const float*)d_in[3];
  const float* masks  = (const float*)d_in[4];
  const float* pcount = (const float*)d_in[5];
  const float* nf     = (const float*)d_in[6];
  float* ws  = (float*)d_ws;
  float* out = (float*)d_out;

  hipMemsetAsync(ws, 0, 68 * sizeof(float), stream);
  fused_all<<<GRID_ALL, 256, 0, stream>>>(logits, adj, nf, pcoord, pts, masks, pcount, ws);
  finalize<<<1, 64, 0, stream>>>(ws, out);
}